// Round 1
// baseline (2964.347 us; speedup 1.0000x reference)
//
#include <hip/hip_runtime.h>

#define EPS 1e-3f

// Workspace layout (float offsets). Weights region is written by setup_k
// every launch; accumulator region is zeroed by hipMemsetAsync every launch.
#define OFF_W1F   0        // [16][64]   fused W1*scale
#define OFF_T1    1024     // [64]       fused bias1
#define OFF_W2AT  1088     // [128][16]  fused W2a^T*scale (transposed!)
#define OFF_T2A   3136     // [128]
#define OFF_W2BF  3264     // [128][64]  fused W2b*scale
#define OFF_T2B   11456    // [64]
#define OFF_MPP   11520    // [64][64]   max-pool partials (64 slots)
// gsum starts at 15616 (S*64 floats), gmax follows (S*64 floats)
#define OFF_ACC   15616

__global__ __launch_bounds__(256) void setup_k(
    const float* __restrict__ W1,
    const float* __restrict__ g1, const float* __restrict__ b1,
    const float* __restrict__ m1, const float* __restrict__ v1,
    const float* __restrict__ W2a,
    const float* __restrict__ g2a, const float* __restrict__ b2a,
    const float* __restrict__ m2a, const float* __restrict__ v2a,
    const float* __restrict__ W2b,
    const float* __restrict__ g2b, const float* __restrict__ b2b,
    const float* __restrict__ m2b, const float* __restrict__ v2b,
    float* __restrict__ ws)
{
    const int t = threadIdx.x;
    for (int i = t; i < 1024; i += 256) {            // W1 fused: [16][64]
        int j = i & 63;
        float s = g1[j] * rsqrtf(v1[j] + EPS);
        ws[OFF_W1F + i] = W1[i] * s;
    }
    for (int i = t; i < 2048; i += 256) {            // W2a fused + transposed: [128][16]
        int k = i >> 4, c = i & 15;
        float s = g2a[k] * rsqrtf(v2a[k] + EPS);
        ws[OFF_W2AT + i] = W2a[c * 128 + k] * s;
    }
    for (int i = t; i < 8192; i += 256) {            // W2b fused: [128][64]
        int j = i & 63;
        float s = g2b[j] * rsqrtf(v2b[j] + EPS);
        ws[OFF_W2BF + i] = W2b[i] * s;
    }
    if (t < 64) {
        float s  = g1[t]  * rsqrtf(v1[t]  + EPS);
        ws[OFF_T1 + t]  = b1[t]  - m1[t]  * s;
        float s2 = g2b[t] * rsqrtf(v2b[t] + EPS);
        ws[OFF_T2B + t] = b2b[t] - m2b[t] * s2;
    }
    if (t < 128) {
        float s = g2a[t] * rsqrtf(v2a[t] + EPS);
        ws[OFF_T2A + t] = b2a[t] - m2a[t] * s;
    }
}

// One thread per point. Weights read through wave-uniform addresses
// (compiler emits s_load + v_fmac with SGPR operand). All register arrays
// are indexed only with compile-time constants after unrolling.
__global__ __launch_bounds__(256) void main_k(
    const float* __restrict__ inputs,
    const int*   __restrict__ unq,
    const float* __restrict__ wk,     // ws base (weights)
    float* __restrict__ mpp,          // [64][64] max-pool partials
    float* __restrict__ gsum,         // [S][64]
    float* __restrict__ gmax,         // [S][64]
    int N)
{
    const int i = blockIdx.x * 256 + threadIdx.x;
    const bool active = (i < N);

    float in[16];
    {
        float4 a0, a1, a2, a3;
        if (active) {
            const float4* p = reinterpret_cast<const float4*>(inputs + (size_t)i * 16);
            a0 = p[0]; a1 = p[1]; a2 = p[2]; a3 = p[3];
        } else {
            a0 = make_float4(0.f, 0.f, 0.f, 0.f);
            a1 = a0; a2 = a0; a3 = a0;
        }
        in[0]=a0.x;  in[1]=a0.y;  in[2]=a0.z;  in[3]=a0.w;
        in[4]=a1.x;  in[5]=a1.y;  in[6]=a1.z;  in[7]=a1.w;
        in[8]=a2.x;  in[9]=a2.y;  in[10]=a2.z; in[11]=a2.w;
        in[12]=a3.x; in[13]=a3.y; in[14]=a3.z; in[15]=a3.w;
    }

    // ---- branch 1: y1 = relu(in @ W1f + t1) ----
    float y1[64];
    #pragma unroll
    for (int j = 0; j < 64; ++j) y1[j] = wk[OFF_T1 + j];
    #pragma unroll
    for (int k = 0; k < 16; ++k) {
        const float a = in[k];
        #pragma unroll
        for (int j = 0; j < 64; ++j)
            y1[j] = fmaf(a, wk[OFF_W1F + k * 64 + j], y1[j]);
    }

    // ---- segment sum + segment max via atomics (values >= 0) ----
    if (active) {
        const int seg = unq[i];
        float* gs = gsum + (size_t)seg * 64;
        float* gm = gmax + (size_t)seg * 64;
        #pragma unroll
        for (int j = 0; j < 64; ++j) {
            const float v = fmaxf(y1[j], 0.f);
            if (v > 0.f) {
                atomicAdd(gs + j, v);
                atomicMax(reinterpret_cast<int*>(gm + j), __float_as_int(v));
            }
        }
    }

    // ---- branch 2 fused: y2 = relu( relu(in @ W2a') @ W2b' ), h never stored ----
    float y2[64];
    #pragma unroll
    for (int j = 0; j < 64; ++j) y2[j] = wk[OFF_T2B + j];
    #pragma unroll 2
    for (int k = 0; k < 128; ++k) {
        float hk = wk[OFF_T2A + k];
        #pragma unroll
        for (int c = 0; c < 16; ++c)
            hk = fmaf(in[c], wk[OFF_W2AT + k * 16 + c], hk);
        hk = fmaxf(hk, 0.f);
        #pragma unroll
        for (int j = 0; j < 64; ++j)
            y2[j] = fmaf(hk, wk[OFF_W2BF + k * 64 + j], y2[j]);
    }

    // ---- global max-pool: fold-reduce 64 channels across 64 lanes ----
    // After 6 stages, z[0] on lane l = max over all 64 lanes of channel l.
    float z[64];
    #pragma unroll
    for (int j = 0; j < 64; ++j) z[j] = active ? fmaxf(y2[j], 0.f) : 0.f;
    const int lane = threadIdx.x & 63;
    #pragma unroll
    for (int b = 5; b >= 0; --b) {
        const int L = 1 << (b + 1);
        float r[64];
        #pragma unroll
        for (int t2 = 0; t2 < 64; ++t2) {
            if (t2 < L) r[t2] = __shfl_xor(z[t2], 1 << b, 64);
        }
        const bool hi = ((lane >> b) & 1) != 0;
        #pragma unroll
        for (int t2 = 0; t2 < 32; ++t2) {
            if (t2 < L / 2) {
                const float lo_v = fmaxf(z[t2],         r[t2]);
                const float hi_v = fmaxf(z[t2 + L / 2], r[t2 + L / 2]);
                z[t2] = hi ? hi_v : lo_v;
            }
        }
    }
    // 64 partial slots to avoid cross-XCD same-line atomic ping-pong
    const int slot = blockIdx.x & 63;
    atomicMax(reinterpret_cast<int*>(mpp + slot * 64 + lane), __float_as_int(z[0]));
}

__global__ __launch_bounds__(256) void out_k(
    const float* __restrict__ mpp,
    const float* __restrict__ gsum,
    const float* __restrict__ gmax,
    float* __restrict__ out,
    int S)
{
    __shared__ float mp[64];
    const int t = threadIdx.x;
    if (t < 64) {
        float m = 0.f;
        #pragma unroll
        for (int s = 0; s < 64; ++s)
            m = fmaxf(m, mpp[s * 64 + t]);
        mp[t] = m;
    }
    __syncthreads();

    const int idx = blockIdx.x * 256 + t;
    const int total = S * 192;
    if (idx < total) {
        const int s = idx / 192;
        const int r = idx - s * 192;
        const int c = r / 3;
        const int g = r - c * 3;
        float v;
        if (g == 0)      v = gsum[(size_t)s * 64 + c];
        else if (g == 1) v = gmax[(size_t)s * 64 + c];   // already >= 0 (init 0)
        else             v = mp[c];
        out[idx] = v;
    }
}

extern "C" void kernel_launch(void* const* d_in, const int* in_sizes, int n_in,
                              void* d_out, int out_size, void* d_ws, size_t ws_size,
                              hipStream_t stream)
{
    const float* inputs = (const float*)d_in[0];
    const int*   unq    = (const int*)d_in[1];
    // d_in[2] = num_segments (device scalar) — derived from out_size instead
    const float* W1  = (const float*)d_in[3];
    const float* g1  = (const float*)d_in[4];
    const float* b1  = (const float*)d_in[5];
    const float* m1  = (const float*)d_in[6];
    const float* v1  = (const float*)d_in[7];
    const float* W2a = (const float*)d_in[8];
    const float* g2a = (const float*)d_in[9];
    const float* b2a = (const float*)d_in[10];
    const float* m2a = (const float*)d_in[11];
    const float* v2a = (const float*)d_in[12];
    const float* W2b = (const float*)d_in[13];
    const float* g2b = (const float*)d_in[14];
    const float* b2b = (const float*)d_in[15];
    const float* m2b = (const float*)d_in[16];
    const float* v2b = (const float*)d_in[17];

    float* ws  = (float*)d_ws;
    float* out = (float*)d_out;
    const int N = in_sizes[0] / 16;
    const int S = out_size / 192;

    float* mpp  = ws + OFF_MPP;
    float* gsum = ws + OFF_ACC;
    float* gmax = gsum + (size_t)S * 64;

    // zero: max-pool partials + gsum + gmax
    hipMemsetAsync(mpp, 0, (size_t)(4096 + 2 * (size_t)S * 64) * sizeof(float), stream);

    setup_k<<<1, 256, 0, stream>>>(W1, g1, b1, m1, v1,
                                   W2a, g2a, b2a, m2a, v2a,
                                   W2b, g2b, b2b, m2b, v2b, ws);

    main_k<<<(N + 255) / 256, 256, 0, stream>>>(inputs, unq, ws, mpp, gsum, gmax, N);

    out_k<<<(S * 192 + 255) / 256, 256, 0, stream>>>(mpp, gsum, gmax, out, S);
}

// Round 2
// 478.241 us; speedup vs baseline: 6.1984x; 6.1984x over previous
//
#include <hip/hip_runtime.h>

#define EPS 1e-3f

// Workspace layout (float offsets). Weights region is written by setup_k
// every launch; accumulator region is zeroed by hipMemsetAsync every launch.
#define OFF_W1F   0        // [16][64]   fused W1*scale
#define OFF_T1    1024     // [64]       fused bias1
#define OFF_W2AT  1088     // [128][16]  fused W2a^T*scale (transposed!)
#define OFF_T2A   3136     // [128]
#define OFF_W2BF  3264     // [128][64]  fused W2b*scale
#define OFF_T2B   11456    // [64]
#define OFF_MPP   11520    // [64][64]   max-pool partials (64 slots)
// gsum starts at 15616 (S*64 floats), gmax follows (S*64 floats)
#define OFF_ACC   15616

__global__ __launch_bounds__(256) void setup_k(
    const float* __restrict__ W1,
    const float* __restrict__ g1, const float* __restrict__ b1,
    const float* __restrict__ m1, const float* __restrict__ v1,
    const float* __restrict__ W2a,
    const float* __restrict__ g2a, const float* __restrict__ b2a,
    const float* __restrict__ m2a, const float* __restrict__ v2a,
    const float* __restrict__ W2b,
    const float* __restrict__ g2b, const float* __restrict__ b2b,
    const float* __restrict__ m2b, const float* __restrict__ v2b,
    float* __restrict__ ws)
{
    const int t = threadIdx.x;
    for (int i = t; i < 1024; i += 256) {            // W1 fused: [16][64]
        int j = i & 63;
        float s = g1[j] * rsqrtf(v1[j] + EPS);
        ws[OFF_W1F + i] = W1[i] * s;
    }
    for (int i = t; i < 2048; i += 256) {            // W2a fused + transposed: [128][16]
        int k = i >> 4, c = i & 15;
        float s = g2a[k] * rsqrtf(v2a[k] + EPS);
        ws[OFF_W2AT + i] = W2a[c * 128 + k] * s;
    }
    for (int i = t; i < 8192; i += 256) {            // W2b fused: [128][64]
        int j = i & 63;
        float s = g2b[j] * rsqrtf(v2b[j] + EPS);
        ws[OFF_W2BF + i] = W2b[i] * s;
    }
    if (t < 64) {
        float s  = g1[t]  * rsqrtf(v1[t]  + EPS);
        ws[OFF_T1 + t]  = b1[t]  - m1[t]  * s;
        float s2 = g2b[t] * rsqrtf(v2b[t] + EPS);
        ws[OFF_T2B + t] = b2b[t] - m2b[t] * s2;
    }
    if (t < 128) {
        float s = g2a[t] * rsqrtf(v2a[t] + EPS);
        ws[OFF_T2A + t] = b2a[t] - m2a[t] * s;
    }
}

// One thread per point. Weights read through wave-uniform addresses
// (s_load + v_fmac with SGPR operand). Segment atomics are lane-coalesced:
// wave-private LDS transpose so 16 consecutive lanes hit 16 consecutive
// channels of one segment row (one 64B line) instead of 64 scattered lines.
__global__ __launch_bounds__(256, 4) void main_k(
    const float* __restrict__ inputs,
    const int*   __restrict__ unq,
    const float* __restrict__ wk,     // ws base (weights)
    float* __restrict__ mpp,          // [64][64] max-pool partials
    float* __restrict__ gsum,         // [S][64]
    float* __restrict__ gmax,         // [S][64]
    int N)
{
    __shared__ float tile[4][64][17]; // wave-private quarter tile [pt][ch], stride 17
    __shared__ int   segs[4][64];

    const int i    = blockIdx.x * 256 + threadIdx.x;
    const bool active = (i < N);
    const int wave = threadIdx.x >> 6;
    const int lane = threadIdx.x & 63;

    float in[16];
    {
        float4 a0, a1, a2, a3;
        if (active) {
            const float4* p = reinterpret_cast<const float4*>(inputs + (size_t)i * 16);
            a0 = p[0]; a1 = p[1]; a2 = p[2]; a3 = p[3];
        } else {
            a0 = make_float4(0.f, 0.f, 0.f, 0.f);
            a1 = a0; a2 = a0; a3 = a0;
        }
        in[0]=a0.x;  in[1]=a0.y;  in[2]=a0.z;  in[3]=a0.w;
        in[4]=a1.x;  in[5]=a1.y;  in[6]=a1.z;  in[7]=a1.w;
        in[8]=a2.x;  in[9]=a2.y;  in[10]=a2.z; in[11]=a2.w;
        in[12]=a3.x; in[13]=a3.y; in[14]=a3.z; in[15]=a3.w;
    }

    segs[wave][lane] = active ? unq[i] : -1;

    // ---- branch 1: y1 = relu(in @ W1f + t1) ----
    float y1[64];
    #pragma unroll
    for (int j = 0; j < 64; ++j) y1[j] = wk[OFF_T1 + j];
    #pragma unroll
    for (int k = 0; k < 16; ++k) {
        const float a = in[k];
        #pragma unroll
        for (int j = 0; j < 64; ++j)
            y1[j] = fmaf(a, wk[OFF_W1F + k * 64 + j], y1[j]);
    }
    #pragma unroll
    for (int j = 0; j < 64; ++j) y1[j] = fmaxf(y1[j], 0.f);

    // ---- coalesced segment sum + max: wave-private LDS transpose ----
    // Quarter q: each thread writes its 16 channels [q*16, q*16+16); then
    // lane l reads point p = 4*pp + (l>>4), channel ch = l&15 and issues
    // atomics at gseg*64 + q*16 + ch -> 16 lanes = one aligned 64B line.
    {
        float* tp = &tile[wave][0][0];
        const int* sp_arr = &segs[wave][0];
        asm volatile("s_waitcnt lgkmcnt(0)" ::: "memory"); // segs visible (wave-private)
        #pragma unroll
        for (int q = 0; q < 4; ++q) {
            #pragma unroll
            for (int c = 0; c < 16; ++c)
                tp[lane * 17 + c] = y1[q * 16 + c];
            asm volatile("s_waitcnt lgkmcnt(0)" ::: "memory");
            __builtin_amdgcn_sched_barrier(0);
            const int ch = lane & 15;
            const int po = lane >> 4;
            #pragma unroll
            for (int pp = 0; pp < 16; ++pp) {
                const int p  = pp * 4 + po;
                const float v = tp[p * 17 + ch];
                const int  sp = sp_arr[p];
                if (sp >= 0) {
                    const size_t off = (size_t)sp * 64 + q * 16 + ch;
                    atomicAdd(gsum + off, v);
                    atomicMax(reinterpret_cast<int*>(gmax + off), __float_as_int(v));
                }
            }
            asm volatile("s_waitcnt lgkmcnt(0)" ::: "memory"); // reads done before rewrite
            __builtin_amdgcn_sched_barrier(0);
        }
    }

    // ---- branch 2 fused: y2 = relu( relu(in @ W2a') @ W2b' ), h never stored ----
    float y2[64];
    #pragma unroll
    for (int j = 0; j < 64; ++j) y2[j] = wk[OFF_T2B + j];
    #pragma unroll 2
    for (int k = 0; k < 128; ++k) {
        float hk = wk[OFF_T2A + k];
        #pragma unroll
        for (int c = 0; c < 16; ++c)
            hk = fmaf(in[c], wk[OFF_W2AT + k * 16 + c], hk);
        hk = fmaxf(hk, 0.f);
        #pragma unroll
        for (int j = 0; j < 64; ++j)
            y2[j] = fmaf(hk, wk[OFF_W2BF + k * 64 + j], y2[j]);
    }

    // ---- global max-pool: fold-reduce 64 channels across 64 lanes ----
    float z[64];
    #pragma unroll
    for (int j = 0; j < 64; ++j) z[j] = active ? fmaxf(y2[j], 0.f) : 0.f;
    #pragma unroll
    for (int b = 5; b >= 0; --b) {
        const int L = 1 << (b + 1);
        float r[64];
        #pragma unroll
        for (int t2 = 0; t2 < 64; ++t2) {
            if (t2 < L) r[t2] = __shfl_xor(z[t2], 1 << b, 64);
        }
        const bool hi = ((lane >> b) & 1) != 0;
        #pragma unroll
        for (int t2 = 0; t2 < 32; ++t2) {
            if (t2 < L / 2) {
                const float lo_v = fmaxf(z[t2],         r[t2]);
                const float hi_v = fmaxf(z[t2 + L / 2], r[t2 + L / 2]);
                z[t2] = hi ? hi_v : lo_v;
            }
        }
    }
    // 64 partial slots to avoid same-line atomic ping-pong across all blocks
    const int slot = blockIdx.x & 63;
    atomicMax(reinterpret_cast<int*>(mpp + slot * 64 + lane), __float_as_int(z[0]));
}

__global__ __launch_bounds__(256) void out_k(
    const float* __restrict__ mpp,
    const float* __restrict__ gsum,
    const float* __restrict__ gmax,
    float* __restrict__ out,
    int S)
{
    __shared__ float mp[64];
    const int t = threadIdx.x;
    if (t < 64) {
        float m = 0.f;
        #pragma unroll
        for (int s = 0; s < 64; ++s)
            m = fmaxf(m, mpp[s * 64 + t]);
        mp[t] = m;
    }
    __syncthreads();

    const int idx = blockIdx.x * 256 + t;
    const int total = S * 192;
    if (idx < total) {
        const int s = idx / 192;
        const int r = idx - s * 192;
        const int c = r / 3;
        const int g = r - c * 3;
        float v;
        if (g == 0)      v = gsum[(size_t)s * 64 + c];
        else if (g == 1) v = gmax[(size_t)s * 64 + c];   // already >= 0 (init 0)
        else             v = mp[c];
        out[idx] = v;
    }
}

extern "C" void kernel_launch(void* const* d_in, const int* in_sizes, int n_in,
                              void* d_out, int out_size, void* d_ws, size_t ws_size,
                              hipStream_t stream)
{
    const float* inputs = (const float*)d_in[0];
    const int*   unq    = (const int*)d_in[1];
    // d_in[2] = num_segments (device scalar) — derived from out_size instead
    const float* W1  = (const float*)d_in[3];
    const float* g1  = (const float*)d_in[4];
    const float* b1  = (const float*)d_in[5];
    const float* m1  = (const float*)d_in[6];
    const float* v1  = (const float*)d_in[7];
    const float* W2a = (const float*)d_in[8];
    const float* g2a = (const float*)d_in[9];
    const float* b2a = (const float*)d_in[10];
    const float* m2a = (const float*)d_in[11];
    const float* v2a = (const float*)d_in[12];
    const float* W2b = (const float*)d_in[13];
    const float* g2b = (const float*)d_in[14];
    const float* b2b = (const float*)d_in[15];
    const float* m2b = (const float*)d_in[16];
    const float* v2b = (const float*)d_in[17];

    float* ws  = (float*)d_ws;
    float* out = (float*)d_out;
    const int N = in_sizes[0] / 16;
    const int S = out_size / 192;

    float* mpp  = ws + OFF_MPP;
    float* gsum = ws + OFF_ACC;
    float* gmax = gsum + (size_t)S * 64;

    // zero: max-pool partials + gsum + gmax
    hipMemsetAsync(mpp, 0, (size_t)(4096 + 2 * (size_t)S * 64) * sizeof(float), stream);

    setup_k<<<1, 256, 0, stream>>>(W1, g1, b1, m1, v1,
                                   W2a, g2a, b2a, m2a, v2a,
                                   W2b, g2b, b2b, m2b, v2b, ws);

    main_k<<<(N + 255) / 256, 256, 0, stream>>>(inputs, unq, ws, mpp, gsum, gmax, N);

    out_k<<<(S * 192 + 255) / 256, 256, 0, stream>>>(mpp, gsum, gmax, out, S);
}

// Round 3
// 448.852 us; speedup vs baseline: 6.6043x; 1.0655x over previous
//
#include <hip/hip_runtime.h>

#define EPS 1e-3f

// ---------------- workspace layout ----------------
// bytes 0..28671  : bf16 fused weights (written by setup_k each launch)
//   w1ft  u16[64][32]   @ byte 0      (4096 B)   rows=out-ch, k 0..15 data, k16=bias, rest 0
//   w2aft u16[128][32]  @ byte 4096   (8192 B)
//   w2bft u16[64][128]  @ byte 12288  (16384 B)
// floats 7168..7231 : t2b f32[64]
// floats 7232..     : mpp [64][64], then gsum [S][64], gmax [S][64]
#define OFF_T2B   7168
#define OFF_MPP   7232
#define OFF_ACC   (OFF_MPP + 4096)

typedef short short8 __attribute__((ext_vector_type(8)));
typedef float f32x4 __attribute__((ext_vector_type(4)));

union U4 { unsigned u[4]; short8 s8; uint4 u4; };

__device__ inline unsigned short f2bf(float f) {           // RNE f32->bf16
    unsigned u = __float_as_uint(f);
    return (unsigned short)((u + 0x7FFFu + ((u >> 16) & 1u)) >> 16);
}

__global__ __launch_bounds__(256) void setup_k(
    const float* __restrict__ W1,
    const float* __restrict__ g1, const float* __restrict__ b1,
    const float* __restrict__ m1, const float* __restrict__ v1,
    const float* __restrict__ W2a,
    const float* __restrict__ g2a, const float* __restrict__ b2a,
    const float* __restrict__ m2a, const float* __restrict__ v2a,
    const float* __restrict__ W2b,
    const float* __restrict__ g2b, const float* __restrict__ b2b,
    const float* __restrict__ m2b, const float* __restrict__ v2b,
    unsigned short* __restrict__ wsu, float* __restrict__ wsf)
{
    const int t = threadIdx.x;
    // w1ft [64][32]: k<16 -> W1[k][ch]*s ; k==16 -> bias ; else 0
    for (int i = t; i < 64 * 32; i += 256) {
        int ch = i >> 5, k = i & 31;
        float s = g1[ch] * rsqrtf(v1[ch] + EPS);
        float val = (k < 16) ? W1[k * 64 + ch] * s
                  : (k == 16 ? b1[ch] - m1[ch] * s : 0.f);
        wsu[i] = f2bf(val);
    }
    // w2aft [128][32]
    for (int i = t; i < 128 * 32; i += 256) {
        int ch = i >> 5, k = i & 31;
        float s = g2a[ch] * rsqrtf(v2a[ch] + EPS);
        float val = (k < 16) ? W2a[k * 128 + ch] * s
                  : (k == 16 ? b2a[ch] - m2a[ch] * s : 0.f);
        wsu[2048 + i] = f2bf(val);
    }
    // w2bft [64][128]
    for (int i = t; i < 64 * 128; i += 256) {
        int ch = i >> 7, k = i & 127;
        float s = g2b[ch] * rsqrtf(v2b[ch] + EPS);
        wsu[2048 + 4096 + i] = f2bf(W2b[k * 64 + ch] * s);
    }
    if (t < 64) {
        float s = g2b[t] * rsqrtf(v2b[t] + EPS);
        wsf[OFF_T2B + t] = b2b[t] - m2b[t] * s;
    }
}

// 512 threads = 8 waves, 64 points per wave, 4 tiles of 16 points each.
__global__ __launch_bounds__(512, 4) void main_k(
    const float* __restrict__ inputs,
    const int*   __restrict__ unq,
    const uint4* __restrict__ wsw,    // weights region of ws (byte 0), 16B units
    const float* __restrict__ wsf,    // ws as floats (for t2b)
    float* __restrict__ mpp,
    float* __restrict__ gsum,
    float* __restrict__ gmax,
    int N)
{
    __shared__ __align__(16) char w1s[4096];     // [64][32] bf16, XOR-swizzled
    __shared__ __align__(16) char w2as[8192];    // [128][32] bf16
    __shared__ __align__(16) char w2bs[16384];   // [64][128] bf16
    __shared__ float t2bs[64];
    __shared__ __align__(16) char scrs[8][4096]; // per-wave scratch (h bf16 / y1 f32)

    const int tid = threadIdx.x;

    // ---- stage fused weights global->LDS with XOR swizzle (byte ^= (row&7)<<4) ----
    {
        // w1ft: 256 units, rowbytes 64 -> row = u>>2
        if (tid < 256) {
            int u = tid;
            *reinterpret_cast<uint4*>(&w1s[(u * 16) ^ (((u >> 2) & 7) << 4)]) = wsw[u];
        }
        // w2aft: 512 units, rowbytes 64
        {
            int u = tid;
            *reinterpret_cast<uint4*>(&w2as[(u * 16) ^ (((u >> 2) & 7) << 4)]) = wsw[256 + u];
        }
        // w2bft: 1024 units, rowbytes 256 -> row = u>>4
        for (int u = tid; u < 1024; u += 512)
            *reinterpret_cast<uint4*>(&w2bs[(u * 16) ^ (((u >> 4) & 7) << 4)]) = wsw[768 + u];
        if (tid < 64) t2bs[tid] = wsf[OFF_T2B + tid];
    }
    __syncthreads();

    const int wv   = tid >> 6;
    const int lane = tid & 63;
    const long wave_pt0 = ((long)blockIdx.x * 8 + wv) * 64;
    if (wave_pt0 >= N) return;

    const int c = lane & 15;          // col / point-in-tile
    const int g = lane >> 4;          // k-group / row-group
    const unsigned swz = (unsigned)(lane & 7) << 4;
    char* scr = scrs[wv];

    // ---- load own point, convert to packed bf16 (pk[j] = {k2j, k2j+1}) ----
    const long ip = wave_pt0 + lane;
    const bool lane_ok = (ip < N);
    const long idx = lane_ok ? ip : (long)(N - 1);
    int myseg = lane_ok ? unq[idx] : -1;

    unsigned pk[8];
    {
        const float4* p = reinterpret_cast<const float4*>(inputs + idx * 16);
        float4 a0 = p[0], a1 = p[1], a2 = p[2], a3 = p[3];
        asm("v_cvt_pk_bf16_f32 %0, %1, %2" : "=v"(pk[0]) : "v"(a0.x), "v"(a0.y));
        asm("v_cvt_pk_bf16_f32 %0, %1, %2" : "=v"(pk[1]) : "v"(a0.z), "v"(a0.w));
        asm("v_cvt_pk_bf16_f32 %0, %1, %2" : "=v"(pk[2]) : "v"(a1.x), "v"(a1.y));
        asm("v_cvt_pk_bf16_f32 %0, %1, %2" : "=v"(pk[3]) : "v"(a1.z), "v"(a1.w));
        asm("v_cvt_pk_bf16_f32 %0, %1, %2" : "=v"(pk[4]) : "v"(a2.x), "v"(a2.y));
        asm("v_cvt_pk_bf16_f32 %0, %1, %2" : "=v"(pk[5]) : "v"(a2.z), "v"(a2.w));
        asm("v_cvt_pk_bf16_f32 %0, %1, %2" : "=v"(pk[6]) : "v"(a3.x), "v"(a3.y));
        asm("v_cvt_pk_bf16_f32 %0, %1, %2" : "=v"(pk[7]) : "v"(a3.z), "v"(a3.w));
    }

    // bias regs for y2 (row-only broadcast within 16-lane groups)
    f32x4 t2br[4];
    #pragma unroll
    for (int mt = 0; mt < 4; ++mt)
        t2br[mt] = *reinterpret_cast<const f32x4*>(&t2bs[mt * 16 + g * 4]);

    float mp[16];
    #pragma unroll
    for (int j = 0; j < 16; ++j) mp[j] = 0.f;

    const f32x4 zero4 = {0.f, 0.f, 0.f, 0.f};

    for (int ti = 0; ti < 4; ++ti) {
        // ---- build B-frag of in^T for this 16-pt tile via shuffles ----
        // lane(c,g) needs in[pt=ti*16+c][k=g*8..g*8+7]; g==2 -> {1,0..}, g==3 -> 0
        U4 bf;
        {
            const int src = ti * 16 + c;
            unsigned s0 = (unsigned)__shfl((int)pk[0], src, 64);
            unsigned s1 = (unsigned)__shfl((int)pk[1], src, 64);
            unsigned s2 = (unsigned)__shfl((int)pk[2], src, 64);
            unsigned s3 = (unsigned)__shfl((int)pk[3], src, 64);
            unsigned s4 = (unsigned)__shfl((int)pk[4], src, 64);
            unsigned s5 = (unsigned)__shfl((int)pk[5], src, 64);
            unsigned s6 = (unsigned)__shfl((int)pk[6], src, 64);
            unsigned s7 = (unsigned)__shfl((int)pk[7], src, 64);
            bool ghi = (lane & 16) != 0;
            bf.u[0] = ghi ? s4 : s0;
            bf.u[1] = ghi ? s5 : s1;
            bf.u[2] = ghi ? s6 : s2;
            bf.u[3] = ghi ? s7 : s3;
            if (lane >= 32) {                       // g==2: k16=1.0 ; g==3: zeros
                bf.u[0] = (lane < 48) ? 0x00003F80u : 0u;
                bf.u[1] = 0u; bf.u[2] = 0u; bf.u[3] = 0u;
            }
        }

        // ================= phase A: y1^T = W1F^T · in^T =================
        f32x4 y1t[4];
        #pragma unroll
        for (int mt = 0; mt < 4; ++mt) {
            short8 a = *reinterpret_cast<const short8*>(
                &w1s[(unsigned)((mt * 16 + c) * 64 + g * 16) ^ swz]);
            y1t[mt] = __builtin_amdgcn_mfma_f32_16x16x32_bf16(a, bf.s8, zero4, 0, 0, 0);
        }
        // relu + store [16 pt][64 ch] f32 to scratch (swizzled)
        #pragma unroll
        for (int mt = 0; mt < 4; ++mt) {
            f32x4 v;
            #pragma unroll
            for (int r = 0; r < 4; ++r) v[r] = fmaxf(y1t[mt][r], 0.f);
            *reinterpret_cast<f32x4*>(&scr[(unsigned)(c * 256 + mt * 64 + g * 16) ^ swz]) = v;
        }
        __builtin_amdgcn_wave_barrier();
        __builtin_amdgcn_sched_barrier(0);

        // ---- coalesced segment atomics: lane(c,g): ch=q*16+c, pt=pp*4+g ----
        #pragma unroll
        for (int pp = 0; pp < 4; ++pp) {
            const int pt  = pp * 4 + g;
            const int seg = __shfl(myseg, ti * 16 + pt, 64);
            const unsigned pswz = (unsigned)(pt & 7) << 4;
            const size_t rowoff = (size_t)(seg < 0 ? 0 : seg) * 64;
            #pragma unroll
            for (int q = 0; q < 4; ++q) {
                const int ch = q * 16 + c;
                const float v = *reinterpret_cast<const float*>(
                    &scr[(unsigned)(pt * 256 + ch * 4) ^ pswz]);
                if (seg >= 0 && v > 0.f) {
                    atomicAdd(gsum + rowoff + ch, v);
                    atomicMax(reinterpret_cast<int*>(gmax + rowoff + ch), __float_as_int(v));
                }
            }
        }
        __builtin_amdgcn_wave_barrier();
        __builtin_amdgcn_sched_barrier(0);

        // ================= phase B: h^T = W2aF^T · in^T =================
        f32x4 hT[8];
        #pragma unroll
        for (int mt = 0; mt < 8; ++mt) {
            short8 a = *reinterpret_cast<const short8*>(
                &w2as[(unsigned)((mt * 16 + c) * 64 + g * 16) ^ swz]);
            hT[mt] = __builtin_amdgcn_mfma_f32_16x16x32_bf16(a, bf.s8, zero4, 0, 0, 0);
        }
        // relu + pack bf16 + store h [16 pt][128 ch] (swizzled)
        #pragma unroll
        for (int mt = 0; mt < 8; ++mt) {
            float h0 = fmaxf(hT[mt][0], 0.f), h1 = fmaxf(hT[mt][1], 0.f);
            float h2 = fmaxf(hT[mt][2], 0.f), h3 = fmaxf(hT[mt][3], 0.f);
            unsigned lo, hi;
            asm("v_cvt_pk_bf16_f32 %0, %1, %2" : "=v"(lo) : "v"(h0), "v"(h1));
            asm("v_cvt_pk_bf16_f32 %0, %1, %2" : "=v"(hi) : "v"(h2), "v"(h3));
            *reinterpret_cast<uint2*>(
                &scr[(unsigned)(c * 256 + mt * 32 + g * 8) ^ swz]) = make_uint2(lo, hi);
        }
        __builtin_amdgcn_wave_barrier();
        __builtin_amdgcn_sched_barrier(0);

        // ================= phase C: y2^T = W2bF^T · relu(h) =================
        f32x4 y2t[4];
        #pragma unroll
        for (int mt = 0; mt < 4; ++mt) y2t[mt] = zero4;
        #pragma unroll
        for (int ks = 0; ks < 4; ++ks) {
            short8 hb = *reinterpret_cast<const short8*>(
                &scr[(unsigned)(c * 256 + ks * 64 + g * 16) ^ swz]);
            #pragma unroll
            for (int mt = 0; mt < 4; ++mt) {
                short8 a = *reinterpret_cast<const short8*>(
                    &w2bs[(unsigned)((mt * 16 + c) * 256 + ks * 64 + g * 16) ^ swz]);
                y2t[mt] = __builtin_amdgcn_mfma_f32_16x16x32_bf16(a, hb, y2t[mt], 0, 0, 0);
            }
        }
        // bias + relu + running max-pool (cols=pts, max over iters then lanes)
        #pragma unroll
        for (int mt = 0; mt < 4; ++mt) {
            #pragma unroll
            for (int r = 0; r < 4; ++r) {
                float v = fmaxf(y2t[mt][r] + t2br[mt][r], 0.f);
                mp[mt * 4 + r] = fmaxf(mp[mt * 4 + r], v);
            }
        }
        __builtin_amdgcn_wave_barrier();
        __builtin_amdgcn_sched_barrier(0);
    }

    // ---- max-pool reduce across the 16 lanes of each row-group ----
    #pragma unroll
    for (int j = 0; j < 16; ++j) {
        float x = mp[j];
        x = fmaxf(x, __shfl_xor(x, 1, 64));
        x = fmaxf(x, __shfl_xor(x, 2, 64));
        x = fmaxf(x, __shfl_xor(x, 4, 64));
        x = fmaxf(x, __shfl_xor(x, 8, 64));
        mp[j] = x;
    }
    if (c == 0) {
        const int slot = ((int)blockIdx.x * 8 + wv) & 63;
        #pragma unroll
        for (int mt = 0; mt < 4; ++mt)
            #pragma unroll
            for (int r = 0; r < 4; ++r)
                atomicMax(reinterpret_cast<int*>(mpp + slot * 64 + mt * 16 + g * 4 + r),
                          __float_as_int(mp[mt * 4 + r]));
    }
}

__global__ __launch_bounds__(256) void out_k(
    const float* __restrict__ mpp,
    const float* __restrict__ gsum,
    const float* __restrict__ gmax,
    float* __restrict__ out,
    int S)
{
    __shared__ float mps[64];
    const int t = threadIdx.x;
    if (t < 64) {
        float m = 0.f;
        #pragma unroll
        for (int s = 0; s < 64; ++s)
            m = fmaxf(m, mpp[s * 64 + t]);
        mps[t] = m;
    }
    __syncthreads();

    const int idx = blockIdx.x * 256 + t;
    const int total = S * 192;
    if (idx < total) {
        const int s = idx / 192;
        const int r = idx - s * 192;
        const int ch = r / 3;
        const int gr = r - ch * 3;
        float v;
        if (gr == 0)      v = gsum[(size_t)s * 64 + ch];
        else if (gr == 1) v = gmax[(size_t)s * 64 + ch];
        else              v = mps[ch];
        out[idx] = v;
    }
}

extern "C" void kernel_launch(void* const* d_in, const int* in_sizes, int n_in,
                              void* d_out, int out_size, void* d_ws, size_t ws_size,
                              hipStream_t stream)
{
    const float* inputs = (const float*)d_in[0];
    const int*   unq    = (const int*)d_in[1];
    const float* W1  = (const float*)d_in[3];
    const float* g1  = (const float*)d_in[4];
    const float* b1  = (const float*)d_in[5];
    const float* m1  = (const float*)d_in[6];
    const float* v1  = (const float*)d_in[7];
    const float* W2a = (const float*)d_in[8];
    const float* g2a = (const float*)d_in[9];
    const float* b2a = (const float*)d_in[10];
    const float* m2a = (const float*)d_in[11];
    const float* v2a = (const float*)d_in[12];
    const float* W2b = (const float*)d_in[13];
    const float* g2b = (const float*)d_in[14];
    const float* b2b = (const float*)d_in[15];
    const float* m2b = (const float*)d_in[16];
    const float* v2b = (const float*)d_in[17];

    float* wsf = (float*)d_ws;
    float* out = (float*)d_out;
    const int N = in_sizes[0] / 16;
    const int S = out_size / 192;

    float* mpp  = wsf + OFF_MPP;
    float* gsum = wsf + OFF_ACC;
    float* gmax = gsum + (size_t)S * 64;

    hipMemsetAsync(mpp, 0, (size_t)(4096 + 2 * (size_t)S * 64) * sizeof(float), stream);

    setup_k<<<1, 256, 0, stream>>>(W1, g1, b1, m1, v1,
                                   W2a, g2a, b2a, m2a, v2a,
                                   W2b, g2b, b2b, m2b, v2b,
                                   (unsigned short*)d_ws, wsf);

    const int nwaves  = (N + 63) / 64;
    const int nblocks = (nwaves + 7) / 8;
    main_k<<<nblocks, 512, 0, stream>>>(inputs, unq, (const uint4*)d_ws, wsf,
                                        mpp, gsum, gmax, N);

    out_k<<<(S * 192 + 255) / 256, 256, 0, stream>>>(mpp, gsum, gmax, out, S);
}

// Round 4
// 384.036 us; speedup vs baseline: 7.7189x; 1.1688x over previous
//
#include <hip/hip_runtime.h>

#define EPS 1e-3f

// ---------------- workspace layout (float/int32 slots) ----------------
// bytes 0..28671 : bf16 fused weights (setup_k each launch)
//   w1ft u16[64][32] @0, w2aft u16[128][32] @4096B, w2bft u16[64][128] @12288B
#define OFF_T2B    7168              // f32[64]
#define OFF_MPP    7232              // f32[64][64] max-pool partials
#define OFF_CNT    11328             // i32[20016]  histogram  (memset w/ mpp)
#define OFF_OFFS   31360             // i32[20001]  CSR offsets
#define OFF_CUR    51392             // i32[20000]  scatter cursors
#define OFF_ORDER  71424             // i32[N]      point ids in segment order
#define OFF_ACC    (OFF_ORDER + 1000000)   // gsum [S][64], gmax [S][64]

typedef short short8 __attribute__((ext_vector_type(8)));
typedef float f32x4 __attribute__((ext_vector_type(4)));

union U4 { unsigned u[4]; short8 s8; };

__device__ inline unsigned short f2bf(float f) {           // RNE f32->bf16
    unsigned u = __float_as_uint(f);
    return (unsigned short)((u + 0x7FFFu + ((u >> 16) & 1u)) >> 16);
}

__global__ __launch_bounds__(256) void setup_k(
    const float* __restrict__ W1,
    const float* __restrict__ g1, const float* __restrict__ b1,
    const float* __restrict__ m1, const float* __restrict__ v1,
    const float* __restrict__ W2a,
    const float* __restrict__ g2a, const float* __restrict__ b2a,
    const float* __restrict__ m2a, const float* __restrict__ v2a,
    const float* __restrict__ W2b,
    const float* __restrict__ g2b, const float* __restrict__ b2b,
    const float* __restrict__ m2b, const float* __restrict__ v2b,
    unsigned short* __restrict__ wsu, float* __restrict__ wsf)
{
    const int t = threadIdx.x;
    for (int i = t; i < 64 * 32; i += 256) {        // w1ft [64ch][32k]
        int ch = i >> 5, k = i & 31;
        float s = g1[ch] * rsqrtf(v1[ch] + EPS);
        float val = (k < 16) ? W1[k * 64 + ch] * s
                  : (k == 16 ? b1[ch] - m1[ch] * s : 0.f);
        wsu[i] = f2bf(val);
    }
    for (int i = t; i < 128 * 32; i += 256) {       // w2aft [128ch][32k]
        int ch = i >> 5, k = i & 31;
        float s = g2a[ch] * rsqrtf(v2a[ch] + EPS);
        float val = (k < 16) ? W2a[k * 128 + ch] * s
                  : (k == 16 ? b2a[ch] - m2a[ch] * s : 0.f);
        wsu[2048 + i] = f2bf(val);
    }
    for (int i = t; i < 64 * 128; i += 256) {       // w2bft [64ch][128k]
        int ch = i >> 7, k = i & 127;
        float s = g2b[ch] * rsqrtf(v2b[ch] + EPS);
        wsu[2048 + 4096 + i] = f2bf(W2b[k * 64 + ch] * s);
    }
    if (t < 64) {
        float s = g2b[t] * rsqrtf(v2b[t] + EPS);
        wsf[OFF_T2B + t] = b2b[t] - m2b[t] * s;
    }
}

__global__ __launch_bounds__(256) void hist_k(
    const int* __restrict__ unq, int* __restrict__ cnt, int N)
{
    const int i = blockIdx.x * 256 + threadIdx.x;
    if (i < N) atomicAdd(&cnt[unq[i]], 1);
}

__global__ __launch_bounds__(1024) void scan_k(
    const int* __restrict__ cnt, int* __restrict__ offs,
    int* __restrict__ cur, int S)
{
    __shared__ int buf[1024];
    __shared__ int carry_s;
    const int t = threadIdx.x;
    if (t == 0) carry_s = 0;
    __syncthreads();
    for (int base = 0; base < S; base += 1024) {
        const int i = base + t;
        int v = (i < S) ? cnt[i] : 0;
        buf[t] = v;
        __syncthreads();
        #pragma unroll
        for (int d = 1; d < 1024; d <<= 1) {
            int x = (t >= d) ? buf[t - d] : 0;
            __syncthreads();
            buf[t] += x;
            __syncthreads();
        }
        const int carry = carry_s;
        const int incl = buf[t] + carry;
        if (i < S) { offs[i] = incl - v; cur[i] = incl - v; }
        __syncthreads();
        if (t == 1023) carry_s = incl;
        __syncthreads();
    }
    if (t == 0) offs[S] = carry_s;
}

__global__ __launch_bounds__(256) void scat_k(
    const int* __restrict__ unq, int* __restrict__ cur,
    int* __restrict__ order, int N)
{
    const int i = blockIdx.x * 256 + threadIdx.x;
    if (i < N) {
        const int pos = atomicAdd(&cur[unq[i]], 1);
        order[pos] = i;
    }
}

// One wave per segment: gather points, MFMA y1, in-register segment
// sum/max (D-frag cols = points -> 16-lane shuffle reduce), single
// coalesced 512B write per segment. Branch 2 + global max-pool fused.
__global__ __launch_bounds__(512, 4) void seg_k(
    const float* __restrict__ inputs,
    const int*   __restrict__ order,
    const int*   __restrict__ offs,
    const uint4* __restrict__ wsw,
    const float* __restrict__ wsf,
    float* __restrict__ mpp,
    float* __restrict__ gsum,
    float* __restrict__ gmax,
    int S)
{
    __shared__ __align__(16) char w1s[4096];     // [64][32] bf16, XOR-swizzled
    __shared__ __align__(16) char w2as[8192];    // [128][32] bf16
    __shared__ __align__(16) char w2bs[16384];   // [64][128] bf16
    __shared__ float t2bs[64];
    __shared__ __align__(16) char scrs[8][4096]; // per-wave h staging (bf16)

    const int tid = threadIdx.x;
    {
        if (tid < 256) {
            int u = tid;
            *reinterpret_cast<uint4*>(&w1s[(u * 16) ^ (((u >> 2) & 7) << 4)]) = wsw[u];
        }
        {
            int u = tid;
            *reinterpret_cast<uint4*>(&w2as[(u * 16) ^ (((u >> 2) & 7) << 4)]) = wsw[256 + u];
        }
        for (int u = tid; u < 1024; u += 512)
            *reinterpret_cast<uint4*>(&w2bs[(u * 16) ^ (((u >> 4) & 7) << 4)]) = wsw[768 + u];
        if (tid < 64) t2bs[tid] = wsf[OFF_T2B + tid];
    }
    __syncthreads();

    const int wv   = tid >> 6;
    const int lane = tid & 63;
    const int seg  = blockIdx.x * 8 + wv;
    if (seg >= S) return;

    const int c = lane & 15;
    const int g = lane >> 4;
    const unsigned swz = (unsigned)(lane & 7) << 4;
    char* scr = scrs[wv];

    const int start = offs[seg];
    const int end   = offs[seg + 1];

    f32x4 t2br[4];
    #pragma unroll
    for (int mt = 0; mt < 4; ++mt)
        t2br[mt] = *reinterpret_cast<const f32x4*>(&t2bs[mt * 16 + g * 4]);

    const f32x4 zero4 = {0.f, 0.f, 0.f, 0.f};
    f32x4 as[4], am[4];
    #pragma unroll
    for (int mt = 0; mt < 4; ++mt) { as[mt] = zero4; am[mt] = zero4; }
    float mp[16];
    #pragma unroll
    for (int j = 0; j < 16; ++j) mp[j] = 0.f;

    for (int base = start; base < end; base += 64) {
        const int nrem = end - base;                 // >0, may exceed 64
        const bool lane_ok = (lane < nrem);
        const int pidx = order[base + (lane_ok ? lane : 0)];

        unsigned pk[8];
        {
            const float4* p = reinterpret_cast<const float4*>(inputs + (size_t)pidx * 16);
            float4 a0 = p[0], a1 = p[1], a2 = p[2], a3 = p[3];
            asm("v_cvt_pk_bf16_f32 %0, %1, %2" : "=v"(pk[0]) : "v"(a0.x), "v"(a0.y));
            asm("v_cvt_pk_bf16_f32 %0, %1, %2" : "=v"(pk[1]) : "v"(a0.z), "v"(a0.w));
            asm("v_cvt_pk_bf16_f32 %0, %1, %2" : "=v"(pk[2]) : "v"(a1.x), "v"(a1.y));
            asm("v_cvt_pk_bf16_f32 %0, %1, %2" : "=v"(pk[3]) : "v"(a1.z), "v"(a1.w));
            asm("v_cvt_pk_bf16_f32 %0, %1, %2" : "=v"(pk[4]) : "v"(a2.x), "v"(a2.y));
            asm("v_cvt_pk_bf16_f32 %0, %1, %2" : "=v"(pk[5]) : "v"(a2.z), "v"(a2.w));
            asm("v_cvt_pk_bf16_f32 %0, %1, %2" : "=v"(pk[6]) : "v"(a3.x), "v"(a3.y));
            asm("v_cvt_pk_bf16_f32 %0, %1, %2" : "=v"(pk[7]) : "v"(a3.z), "v"(a3.w));
            if (!lane_ok) {
                #pragma unroll
                for (int j = 0; j < 8; ++j) pk[j] = 0u;
            }
        }

        for (int ti = 0; ti < 4; ++ti) {
            if (ti * 16 >= nrem) break;              // wave-uniform
            const bool act = (ti * 16 + c) < nrem;   // this column's point is real

            // ---- B-frag of in^T (bias slot 1.0 only for active points) ----
            U4 bf;
            {
                const int src = ti * 16 + c;
                unsigned s0 = (unsigned)__shfl((int)pk[0], src, 64);
                unsigned s1 = (unsigned)__shfl((int)pk[1], src, 64);
                unsigned s2 = (unsigned)__shfl((int)pk[2], src, 64);
                unsigned s3 = (unsigned)__shfl((int)pk[3], src, 64);
                unsigned s4 = (unsigned)__shfl((int)pk[4], src, 64);
                unsigned s5 = (unsigned)__shfl((int)pk[5], src, 64);
                unsigned s6 = (unsigned)__shfl((int)pk[6], src, 64);
                unsigned s7 = (unsigned)__shfl((int)pk[7], src, 64);
                bool ghi = (lane & 16) != 0;
                bf.u[0] = ghi ? s4 : s0;
                bf.u[1] = ghi ? s5 : s1;
                bf.u[2] = ghi ? s6 : s2;
                bf.u[3] = ghi ? s7 : s3;
                if (lane >= 32) {
                    bf.u[0] = (lane < 48 && act) ? 0x00003F80u : 0u;
                    bf.u[1] = 0u; bf.u[2] = 0u; bf.u[3] = 0u;
                }
            }

            // ===== phase A: y1^T tile; accumulate segment sum/max in-reg =====
            #pragma unroll
            for (int mt = 0; mt < 4; ++mt) {
                short8 a = *reinterpret_cast<const short8*>(
                    &w1s[(unsigned)((mt * 16 + c) * 64 + g * 16) ^ swz]);
                f32x4 y1t = __builtin_amdgcn_mfma_f32_16x16x32_bf16(a, bf.s8, zero4, 0, 0, 0);
                #pragma unroll
                for (int r = 0; r < 4; ++r) {
                    float v = fmaxf(y1t[r], 0.f);    // inactive cols -> 0
                    as[mt][r] += v;
                    am[mt][r]  = fmaxf(am[mt][r], v);
                }
            }

            // ===== phase B: h^T = W2aF^T · in^T, relu, bf16 -> scr =====
            #pragma unroll
            for (int mt = 0; mt < 8; ++mt) {
                short8 a = *reinterpret_cast<const short8*>(
                    &w2as[(unsigned)((mt * 16 + c) * 64 + g * 16) ^ swz]);
                f32x4 hT = __builtin_amdgcn_mfma_f32_16x16x32_bf16(a, bf.s8, zero4, 0, 0, 0);
                float h0 = fmaxf(hT[0], 0.f), h1 = fmaxf(hT[1], 0.f);
                float h2 = fmaxf(hT[2], 0.f), h3 = fmaxf(hT[3], 0.f);
                unsigned lo, hi;
                asm("v_cvt_pk_bf16_f32 %0, %1, %2" : "=v"(lo) : "v"(h0), "v"(h1));
                asm("v_cvt_pk_bf16_f32 %0, %1, %2" : "=v"(hi) : "v"(h2), "v"(h3));
                *reinterpret_cast<uint2*>(
                    &scr[(unsigned)(c * 256 + mt * 32 + g * 8) ^ swz]) = make_uint2(lo, hi);
            }
            __builtin_amdgcn_wave_barrier();
            __builtin_amdgcn_sched_barrier(0);

            // ===== phase C: y2^T = W2bF^T · h ; masked global max-pool =====
            f32x4 y2t[4];
            #pragma unroll
            for (int mt = 0; mt < 4; ++mt) y2t[mt] = zero4;
            #pragma unroll
            for (int ks = 0; ks < 4; ++ks) {
                short8 hb = *reinterpret_cast<const short8*>(
                    &scr[(unsigned)(c * 256 + ks * 64 + g * 16) ^ swz]);
                #pragma unroll
                for (int mt = 0; mt < 4; ++mt) {
                    short8 a = *reinterpret_cast<const short8*>(
                        &w2bs[(unsigned)((mt * 16 + c) * 256 + ks * 64 + g * 16) ^ swz]);
                    y2t[mt] = __builtin_amdgcn_mfma_f32_16x16x32_bf16(a, hb, y2t[mt], 0, 0, 0);
                }
            }
            #pragma unroll
            for (int mt = 0; mt < 4; ++mt) {
                #pragma unroll
                for (int r = 0; r < 4; ++r) {
                    float v = fmaxf(y2t[mt][r] + t2br[mt][r], 0.f);
                    if (act) mp[mt * 4 + r] = fmaxf(mp[mt * 4 + r], v);
                }
            }
            __builtin_amdgcn_wave_barrier();
            __builtin_amdgcn_sched_barrier(0);
        }
    }

    // ---- reduce segment sum/max across the 16 column-lanes ----
    #pragma unroll
    for (int mt = 0; mt < 4; ++mt) {
        #pragma unroll
        for (int r = 0; r < 4; ++r) {
            float xs = as[mt][r], xm = am[mt][r];
            xs += __shfl_xor(xs, 1, 64);  xm = fmaxf(xm, __shfl_xor(xm, 1, 64));
            xs += __shfl_xor(xs, 2, 64);  xm = fmaxf(xm, __shfl_xor(xm, 2, 64));
            xs += __shfl_xor(xs, 4, 64);  xm = fmaxf(xm, __shfl_xor(xm, 4, 64));
            xs += __shfl_xor(xs, 8, 64);  xm = fmaxf(xm, __shfl_xor(xm, 8, 64));
            as[mt][r] = xs; am[mt][r] = xm;
        }
    }
    if (c < 4) {   // lane(c,g) writes channels c*16 + g*4 .. +3 (coalesced 256B x2)
        f32x4 vs = (c == 0) ? as[0] : (c == 1) ? as[1] : (c == 2) ? as[2] : as[3];
        f32x4 vm = (c == 0) ? am[0] : (c == 1) ? am[1] : (c == 2) ? am[2] : am[3];
        const size_t o = (size_t)seg * 64 + c * 16 + g * 4;
        *reinterpret_cast<f32x4*>(gsum + o) = vs;
        *reinterpret_cast<f32x4*>(gmax + o) = vm;
    }

    // ---- global max-pool partials ----
    #pragma unroll
    for (int j = 0; j < 16; ++j) {
        float x = mp[j];
        x = fmaxf(x, __shfl_xor(x, 1, 64));
        x = fmaxf(x, __shfl_xor(x, 2, 64));
        x = fmaxf(x, __shfl_xor(x, 4, 64));
        x = fmaxf(x, __shfl_xor(x, 8, 64));
        mp[j] = x;
    }
    if (c == 0) {
        const int slot = seg & 63;
        #pragma unroll
        for (int mt = 0; mt < 4; ++mt)
            #pragma unroll
            for (int r = 0; r < 4; ++r)
                atomicMax(reinterpret_cast<int*>(mpp + slot * 64 + mt * 16 + g * 4 + r),
                          __float_as_int(mp[mt * 4 + r]));
    }
}

__global__ __launch_bounds__(256) void out_k(
    const float* __restrict__ mpp,
    const float* __restrict__ gsum,
    const float* __restrict__ gmax,
    float* __restrict__ out,
    int S)
{
    __shared__ float mps[64];
    const int t = threadIdx.x;
    if (t < 64) {
        float m = 0.f;
        #pragma unroll
        for (int s = 0; s < 64; ++s)
            m = fmaxf(m, mpp[s * 64 + t]);
        mps[t] = m;
    }
    __syncthreads();

    const int idx = blockIdx.x * 256 + t;
    const int total = S * 192;
    if (idx < total) {
        const int s = idx / 192;
        const int r = idx - s * 192;
        const int ch = r / 3;
        const int gr = r - ch * 3;
        float v;
        if (gr == 0)      v = gsum[(size_t)s * 64 + ch];
        else if (gr == 1) v = gmax[(size_t)s * 64 + ch];
        else              v = mps[ch];
        out[idx] = v;
    }
}

extern "C" void kernel_launch(void* const* d_in, const int* in_sizes, int n_in,
                              void* d_out, int out_size, void* d_ws, size_t ws_size,
                              hipStream_t stream)
{
    const float* inputs = (const float*)d_in[0];
    const int*   unq    = (const int*)d_in[1];
    const float* W1  = (const float*)d_in[3];
    const float* g1  = (const float*)d_in[4];
    const float* b1  = (const float*)d_in[5];
    const float* m1  = (const float*)d_in[6];
    const float* v1  = (const float*)d_in[7];
    const float* W2a = (const float*)d_in[8];
    const float* g2a = (const float*)d_in[9];
    const float* b2a = (const float*)d_in[10];
    const float* m2a = (const float*)d_in[11];
    const float* v2a = (const float*)d_in[12];
    const float* W2b = (const float*)d_in[13];
    const float* g2b = (const float*)d_in[14];
    const float* b2b = (const float*)d_in[15];
    const float* m2b = (const float*)d_in[16];
    const float* v2b = (const float*)d_in[17];

    float* wsf = (float*)d_ws;
    float* out = (float*)d_out;
    const int N = in_sizes[0] / 16;
    const int S = out_size / 192;

    float* mpp   = wsf + OFF_MPP;
    int*   cnt   = (int*)(wsf + OFF_CNT);
    int*   offs  = (int*)(wsf + OFF_OFFS);
    int*   cur   = (int*)(wsf + OFF_CUR);
    int*   order = (int*)(wsf + OFF_ORDER);
    float* gsum  = wsf + OFF_ACC;
    float* gmax  = gsum + (size_t)S * 64;

    // zero mpp (4096 f) + cnt (contiguous) in one shot
    hipMemsetAsync(mpp, 0, (size_t)(4096 + 20016) * sizeof(float), stream);

    setup_k<<<1, 256, 0, stream>>>(W1, g1, b1, m1, v1,
                                   W2a, g2a, b2a, m2a, v2a,
                                   W2b, g2b, b2b, m2b, v2b,
                                   (unsigned short*)d_ws, wsf);

    const int nb = (N + 255) / 256;
    hist_k<<<nb, 256, 0, stream>>>(unq, cnt, N);
    scan_k<<<1, 1024, 0, stream>>>(cnt, offs, cur, S);
    scat_k<<<nb, 256, 0, stream>>>(unq, cur, order, N);

    seg_k<<<(S + 7) / 8, 512, 0, stream>>>(inputs, order, offs,
                                           (const uint4*)d_ws, wsf,
                                           mpp, gsum, gmax, S);

    out_k<<<(S * 192 + 255) / 256, 256, 0, stream>>>(mpp, gsum, gmax, out, S);
}

// Round 5
// 217.965 us; speedup vs baseline: 13.6001x; 1.7619x over previous
//
#include <hip/hip_runtime.h>

#define EPS 1e-3f

// ---------------- workspace layout (float slots) ----------------
// bytes 0..28671 : bf16 fused weights (setup_k each launch)
//   w1ft u16[64][32] @0, w2aft u16[128][32] @4096B, w2bft u16[64][128] @12288B
#define OFF_T2B    7168              // f32[64]
#define OFF_MPP    7232              // f32[64][64] max-pool partials (memset)
#define OFF_CNT    11328             // i32[20016]  histogram (memset w/ mpp)
#define OFF_OFFS   31344             // i32[S+1] CSR offsets
#define OFF_CUR    51360             // i32[S]   scatter cursors
#define OFF_INPS   71424             // bf16[N][16] sorted inputs (32B/pt) -- needs ~33MB ws
// total ws need: (71424 + N*8) floats  ~= 32.6 MB for N=1e6

typedef short short8 __attribute__((ext_vector_type(8)));
typedef float f32x4 __attribute__((ext_vector_type(4)));

union U4 { unsigned u[4]; short8 s8; };

__device__ inline unsigned short f2bf(float f) {           // RNE f32->bf16
    unsigned u = __float_as_uint(f);
    return (unsigned short)((u + 0x7FFFu + ((u >> 16) & 1u)) >> 16);
}

__global__ __launch_bounds__(256) void setup_k(
    const float* __restrict__ W1,
    const float* __restrict__ g1, const float* __restrict__ b1,
    const float* __restrict__ m1, const float* __restrict__ v1,
    const float* __restrict__ W2a,
    const float* __restrict__ g2a, const float* __restrict__ b2a,
    const float* __restrict__ m2a, const float* __restrict__ v2a,
    const float* __restrict__ W2b,
    const float* __restrict__ g2b, const float* __restrict__ b2b,
    const float* __restrict__ m2b, const float* __restrict__ v2b,
    unsigned short* __restrict__ wsu, float* __restrict__ wsf)
{
    const int t = threadIdx.x;
    for (int i = t; i < 64 * 32; i += 256) {        // w1ft [64ch][32k]
        int ch = i >> 5, k = i & 31;
        float s = g1[ch] * rsqrtf(v1[ch] + EPS);
        float val = (k < 16) ? W1[k * 64 + ch] * s
                  : (k == 16 ? b1[ch] - m1[ch] * s : 0.f);
        wsu[i] = f2bf(val);
    }
    for (int i = t; i < 128 * 32; i += 256) {       // w2aft [128ch][32k]
        int ch = i >> 5, k = i & 31;
        float s = g2a[ch] * rsqrtf(v2a[ch] + EPS);
        float val = (k < 16) ? W2a[k * 128 + ch] * s
                  : (k == 16 ? b2a[ch] - m2a[ch] * s : 0.f);
        wsu[2048 + i] = f2bf(val);
    }
    for (int i = t; i < 64 * 128; i += 256) {       // w2bft [64ch][128k]
        int ch = i >> 7, k = i & 127;
        float s = g2b[ch] * rsqrtf(v2b[ch] + EPS);
        wsu[2048 + 4096 + i] = f2bf(W2b[k * 64 + ch] * s);
    }
    if (t < 64) {
        float s = g2b[t] * rsqrtf(v2b[t] + EPS);
        wsf[OFF_T2B + t] = b2b[t] - m2b[t] * s;
    }
}

__global__ __launch_bounds__(256) void hist_k(
    const int* __restrict__ unq, int* __restrict__ cnt, int N)
{
    const int i = blockIdx.x * 256 + threadIdx.x;
    if (i < N) atomicAdd(&cnt[unq[i]], 1);
}

// serial-per-thread two-pass scan: thread t owns elements [t*E, t*E+E)
__global__ __launch_bounds__(1024) void scan_k(
    const int* __restrict__ cnt, int* __restrict__ offs,
    int* __restrict__ cur, int S)
{
    __shared__ int tot[1024];
    const int t = threadIdx.x;
    const int E = (S + 1023) >> 10;
    const int i0 = t * E;
    int run = 0;
    for (int j = 0; j < E; ++j) {
        const int i = i0 + j;
        run += (i < S) ? cnt[i] : 0;
    }
    tot[t] = run;
    __syncthreads();
    for (int d = 1; d < 1024; d <<= 1) {
        int x = (t >= d) ? tot[t - d] : 0;
        __syncthreads();
        tot[t] += x;
        __syncthreads();
    }
    int base = (t == 0) ? 0 : tot[t - 1];
    for (int j = 0; j < E; ++j) {
        const int i = i0 + j;
        if (i < S) {
            offs[i] = base;
            cur[i]  = base;
            base += cnt[i];
        }
    }
    if (t == 1023) offs[S] = tot[1023];
}

// Fused scatter + branch2 + global max-pool.
// Per point: read f32 input coalesced, cvt bf16, scatter 32B row to inpS[pos];
// per 16-pt tile: MFMA h = W2a*in, y2 = W2b*relu(h); block-reduced max-pool.
__global__ __launch_bounds__(512, 2) void scatbr2_k(
    const float* __restrict__ inputs,
    const int*   __restrict__ unq,
    int*         __restrict__ cur,
    uint4*       __restrict__ inpS,
    const uint4* __restrict__ wsw,
    const float* __restrict__ wsf,
    float* __restrict__ mpp,
    int N)
{
    __shared__ __align__(16) char w2as[8192];    // [128][32] bf16, XOR-swizzled
    __shared__ __align__(16) char w2bs[16384];   // [64][128] bf16
    __shared__ float t2bs[64];
    __shared__ float mpb[64];
    __shared__ __align__(16) char scrs[8][4096]; // per-wave h staging (bf16)

    const int tid = threadIdx.x;
    {
        int u = tid;                              // w2aft: 512 units, rowbytes 64
        *reinterpret_cast<uint4*>(&w2as[(u * 16) ^ (((u >> 2) & 7) << 4)]) = wsw[256 + u];
        for (int v = tid; v < 1024; v += 512)     // w2bft: 1024 units, rowbytes 256
            *reinterpret_cast<uint4*>(&w2bs[(v * 16) ^ (((v >> 4) & 7) << 4)]) = wsw[768 + v];
        if (tid < 64) { t2bs[tid] = wsf[OFF_T2B + tid]; mpb[tid] = 0.f; }
    }
    __syncthreads();

    const int wv   = tid >> 6;
    const int lane = tid & 63;
    const int c = lane & 15;
    const int g = lane >> 4;
    const unsigned swz = (unsigned)(lane & 7) << 4;
    char* scr = scrs[wv];

    const long wave_pt0 = (long)blockIdx.x * 512 + wv * 64;
    const long i  = wave_pt0 + lane;
    const bool lane_ok = (i < N);
    const long idx = lane_ok ? i : (long)(N - 1);
    const long nrem_w = (long)N - wave_pt0;       // may be <=0 for tail waves

    // ---- load own point, cvt packed bf16, scatter to segment-sorted array ----
    unsigned pk[8];
    {
        const float4* p = reinterpret_cast<const float4*>(inputs + idx * 16);
        float4 a0 = p[0], a1 = p[1], a2 = p[2], a3 = p[3];
        asm("v_cvt_pk_bf16_f32 %0, %1, %2" : "=v"(pk[0]) : "v"(a0.x), "v"(a0.y));
        asm("v_cvt_pk_bf16_f32 %0, %1, %2" : "=v"(pk[1]) : "v"(a0.z), "v"(a0.w));
        asm("v_cvt_pk_bf16_f32 %0, %1, %2" : "=v"(pk[2]) : "v"(a1.x), "v"(a1.y));
        asm("v_cvt_pk_bf16_f32 %0, %1, %2" : "=v"(pk[3]) : "v"(a1.z), "v"(a1.w));
        asm("v_cvt_pk_bf16_f32 %0, %1, %2" : "=v"(pk[4]) : "v"(a2.x), "v"(a2.y));
        asm("v_cvt_pk_bf16_f32 %0, %1, %2" : "=v"(pk[5]) : "v"(a2.z), "v"(a2.w));
        asm("v_cvt_pk_bf16_f32 %0, %1, %2" : "=v"(pk[6]) : "v"(a3.x), "v"(a3.y));
        asm("v_cvt_pk_bf16_f32 %0, %1, %2" : "=v"(pk[7]) : "v"(a3.z), "v"(a3.w));
        if (!lane_ok) {
            #pragma unroll
            for (int j = 0; j < 8; ++j) pk[j] = 0u;
        }
    }
    if (lane_ok) {
        const int seg = unq[idx];
        const int pos = atomicAdd(&cur[seg], 1);
        inpS[(size_t)pos * 2]     = make_uint4(pk[0], pk[1], pk[2], pk[3]);
        inpS[(size_t)pos * 2 + 1] = make_uint4(pk[4], pk[5], pk[6], pk[7]);
    }

    f32x4 t2br[4];
    #pragma unroll
    for (int mt = 0; mt < 4; ++mt)
        t2br[mt] = *reinterpret_cast<const f32x4*>(&t2bs[mt * 16 + g * 4]);

    const f32x4 zero4 = {0.f, 0.f, 0.f, 0.f};
    float mp[16];
    #pragma unroll
    for (int j = 0; j < 16; ++j) mp[j] = 0.f;

    for (int ti = 0; ti < 4; ++ti) {
        if ((long)ti * 16 >= nrem_w) break;              // wave-uniform
        const bool act = (long)(ti * 16 + c) < nrem_w;

        // ---- B-frag of in^T via shuffles ----
        U4 bf;
        {
            const int src = ti * 16 + c;
            unsigned s0 = (unsigned)__shfl((int)pk[0], src, 64);
            unsigned s1 = (unsigned)__shfl((int)pk[1], src, 64);
            unsigned s2 = (unsigned)__shfl((int)pk[2], src, 64);
            unsigned s3 = (unsigned)__shfl((int)pk[3], src, 64);
            unsigned s4 = (unsigned)__shfl((int)pk[4], src, 64);
            unsigned s5 = (unsigned)__shfl((int)pk[5], src, 64);
            unsigned s6 = (unsigned)__shfl((int)pk[6], src, 64);
            unsigned s7 = (unsigned)__shfl((int)pk[7], src, 64);
            bool ghi = (lane & 16) != 0;
            bf.u[0] = ghi ? s4 : s0;
            bf.u[1] = ghi ? s5 : s1;
            bf.u[2] = ghi ? s6 : s2;
            bf.u[3] = ghi ? s7 : s3;
            if (lane >= 32) {
                bf.u[0] = (lane < 48 && act) ? 0x00003F80u : 0u;
                bf.u[1] = 0u; bf.u[2] = 0u; bf.u[3] = 0u;
            }
        }

        // ===== h^T = W2aF^T * in^T, relu, bf16 -> scr =====
        #pragma unroll
        for (int mt = 0; mt < 8; ++mt) {
            short8 a = *reinterpret_cast<const short8*>(
                &w2as[(unsigned)((mt * 16 + c) * 64 + g * 16) ^ swz]);
            f32x4 hT = __builtin_amdgcn_mfma_f32_16x16x32_bf16(a, bf.s8, zero4, 0, 0, 0);
            float h0 = fmaxf(hT[0], 0.f), h1 = fmaxf(hT[1], 0.f);
            float h2 = fmaxf(hT[2], 0.f), h3 = fmaxf(hT[3], 0.f);
            unsigned lo, hi;
            asm("v_cvt_pk_bf16_f32 %0, %1, %2" : "=v"(lo) : "v"(h0), "v"(h1));
            asm("v_cvt_pk_bf16_f32 %0, %1, %2" : "=v"(hi) : "v"(h2), "v"(h3));
            *reinterpret_cast<uint2*>(
                &scr[(unsigned)(c * 256 + mt * 32 + g * 8) ^ swz]) = make_uint2(lo, hi);
        }
        __builtin_amdgcn_wave_barrier();
        asm volatile("s_waitcnt lgkmcnt(0)" ::: "memory");
        __builtin_amdgcn_sched_barrier(0);

        // ===== y2^T = W2bF^T * h ; masked running max-pool =====
        f32x4 y2t[4];
        #pragma unroll
        for (int mt = 0; mt < 4; ++mt) y2t[mt] = zero4;
        #pragma unroll
        for (int ks = 0; ks < 4; ++ks) {
            short8 hb = *reinterpret_cast<const short8*>(
                &scr[(unsigned)(c * 256 + ks * 64 + g * 16) ^ swz]);
            #pragma unroll
            for (int mt = 0; mt < 4; ++mt) {
                short8 a = *reinterpret_cast<const short8*>(
                    &w2bs[(unsigned)((mt * 16 + c) * 256 + ks * 64 + g * 16) ^ swz]);
                y2t[mt] = __builtin_amdgcn_mfma_f32_16x16x32_bf16(a, hb, y2t[mt], 0, 0, 0);
            }
        }
        #pragma unroll
        for (int mt = 0; mt < 4; ++mt) {
            #pragma unroll
            for (int r = 0; r < 4; ++r) {
                float v = fmaxf(y2t[mt][r] + t2br[mt][r], 0.f);
                if (act) mp[mt * 4 + r] = fmaxf(mp[mt * 4 + r], v);
            }
        }
        __builtin_amdgcn_wave_barrier();
        asm volatile("s_waitcnt lgkmcnt(0)" ::: "memory");
        __builtin_amdgcn_sched_barrier(0);
    }

    // ---- block max-pool reduce: 16-lane shfl, LDS atomic, one global line ----
    #pragma unroll
    for (int j = 0; j < 16; ++j) {
        float x = mp[j];
        x = fmaxf(x, __shfl_xor(x, 1, 64));
        x = fmaxf(x, __shfl_xor(x, 2, 64));
        x = fmaxf(x, __shfl_xor(x, 4, 64));
        x = fmaxf(x, __shfl_xor(x, 8, 64));
        mp[j] = x;
    }
    if (c == 0) {
        #pragma unroll
        for (int mt = 0; mt < 4; ++mt)
            #pragma unroll
            for (int r = 0; r < 4; ++r)
                atomicMax(reinterpret_cast<int*>(&mpb[mt * 16 + g * 4 + r]),
                          __float_as_int(mp[mt * 4 + r]));
    }
    __syncthreads();
    if (tid < 64)
        atomicMax(reinterpret_cast<int*>(mpp + (blockIdx.x & 63) * 64 + tid),
                  __float_as_int(mpb[tid]));
}

// One wave per segment on SORTED bf16 inputs: B-frag = direct 16B load,
// 4 MFMA/tile, in-register sum/max, write final shuffled 768B row to out.
__global__ __launch_bounds__(512) void seg1_k(
    const uint4* __restrict__ inpS,
    const int*   __restrict__ offs,
    const uint4* __restrict__ wsw,
    const float* __restrict__ mpp,
    float* __restrict__ out,
    int S, int Npt)
{
    __shared__ __align__(16) char w1s[4096];     // [64][32] bf16, XOR-swizzled
    __shared__ float mps[64];
    __shared__ float scr3[8][192];

    const int tid = threadIdx.x;
    if (tid < 256) {
        int u = tid;
        *reinterpret_cast<uint4*>(&w1s[(u * 16) ^ (((u >> 2) & 7) << 4)]) = wsw[u];
    }
    if (tid < 64) {
        float m = 0.f;
        #pragma unroll
        for (int s = 0; s < 64; ++s)
            m = fmaxf(m, mpp[s * 64 + tid]);
        mps[tid] = m;
    }
    __syncthreads();

    const int wv   = tid >> 6;
    const int lane = tid & 63;
    const int seg  = blockIdx.x * 8 + wv;
    if (seg >= S) return;

    const int c = lane & 15;
    const int g = lane >> 4;
    const unsigned swz = (unsigned)(lane & 7) << 4;

    const int start = offs[seg];
    const int end   = offs[seg + 1];

    const f32x4 zero4 = {0.f, 0.f, 0.f, 0.f};
    f32x4 as[4], am[4];
    #pragma unroll
    for (int mt = 0; mt < 4; ++mt) { as[mt] = zero4; am[mt] = zero4; }

    for (int base = start; base < end; base += 64) {
        const int nrem = end - base;
        #pragma unroll
        for (int ti = 0; ti < 4; ++ti) {
            if (ti * 16 >= nrem) break;                 // wave-uniform
            const bool act = (ti * 16 + c) < nrem;
            int row = base + ti * 16 + c;
            row = min(row, Npt - 1);

            U4 bf;
            {
                uint4 q = inpS[(size_t)row * 2 + (g & 1)];
                const bool data = (g < 2) && act;
                bf.u[0] = data ? q.x : ((g == 2 && act) ? 0x00003F80u : 0u);
                bf.u[1] = data ? q.y : 0u;
                bf.u[2] = data ? q.z : 0u;
                bf.u[3] = data ? q.w : 0u;
            }
            #pragma unroll
            for (int mt = 0; mt < 4; ++mt) {
                short8 a = *reinterpret_cast<const short8*>(
                    &w1s[(unsigned)((mt * 16 + c) * 64 + g * 16) ^ swz]);
                f32x4 y1t = __builtin_amdgcn_mfma_f32_16x16x32_bf16(a, bf.s8, zero4, 0, 0, 0);
                #pragma unroll
                for (int r = 0; r < 4; ++r) {
                    float v = fmaxf(y1t[r], 0.f);       // inactive cols give 0
                    as[mt][r] += v;
                    am[mt][r]  = fmaxf(am[mt][r], v);
                }
            }
        }
    }

    // ---- reduce across the 16 column-lanes ----
    #pragma unroll
    for (int mt = 0; mt < 4; ++mt) {
        #pragma unroll
        for (int r = 0; r < 4; ++r) {
            float xs = as[mt][r], xm = am[mt][r];
            xs += __shfl_xor(xs, 1, 64);  xm = fmaxf(xm, __shfl_xor(xm, 1, 64));
            xs += __shfl_xor(xs, 2, 64);  xm = fmaxf(xm, __shfl_xor(xm, 2, 64));
            xs += __shfl_xor(xs, 4, 64);  xm = fmaxf(xm, __shfl_xor(xm, 4, 64));
            xs += __shfl_xor(xs, 8, 64);  xm = fmaxf(xm, __shfl_xor(xm, 8, 64));
            as[mt][r] = xs; am[mt][r] = xm;
        }
    }

    // ---- stage channel-shuffled 192 floats, then 3 coalesced line writes ----
    float* sr = scr3[wv];
    if (c == 0) {
        #pragma unroll
        for (int mt = 0; mt < 4; ++mt)
            #pragma unroll
            for (int r = 0; r < 4; ++r) {
                const int ch = mt * 16 + g * 4 + r;
                sr[ch * 3 + 0] = as[mt][r];
                sr[ch * 3 + 1] = am[mt][r];
            }
    }
    sr[lane * 3 + 2] = mps[lane];
    __builtin_amdgcn_wave_barrier();
    asm volatile("s_waitcnt lgkmcnt(0)" ::: "memory");
    __builtin_amdgcn_sched_barrier(0);

    float* o = out + (size_t)seg * 192;
    #pragma unroll
    for (int p = 0; p < 3; ++p)
        o[p * 64 + lane] = sr[p * 64 + lane];
}

extern "C" void kernel_launch(void* const* d_in, const int* in_sizes, int n_in,
                              void* d_out, int out_size, void* d_ws, size_t ws_size,
                              hipStream_t stream)
{
    const float* inputs = (const float*)d_in[0];
    const int*   unq    = (const int*)d_in[1];
    const float* W1  = (const float*)d_in[3];
    const float* g1  = (const float*)d_in[4];
    const float* b1  = (const float*)d_in[5];
    const float* m1  = (const float*)d_in[6];
    const float* v1  = (const float*)d_in[7];
    const float* W2a = (const float*)d_in[8];
    const float* g2a = (const float*)d_in[9];
    const float* b2a = (const float*)d_in[10];
    const float* m2a = (const float*)d_in[11];
    const float* v2a = (const float*)d_in[12];
    const float* W2b = (const float*)d_in[13];
    const float* g2b = (const float*)d_in[14];
    const float* b2b = (const float*)d_in[15];
    const float* m2b = (const float*)d_in[16];
    const float* v2b = (const float*)d_in[17];

    float* wsf = (float*)d_ws;
    float* out = (float*)d_out;
    const int N = in_sizes[0] / 16;
    const int S = out_size / 192;

    float* mpp  = wsf + OFF_MPP;
    int*   cnt  = (int*)(wsf + OFF_CNT);
    int*   offs = (int*)(wsf + OFF_OFFS);
    int*   cur  = (int*)(wsf + OFF_CUR);
    uint4* inpS = (uint4*)(wsf + OFF_INPS);

    // zero mpp + cnt (contiguous region)
    hipMemsetAsync(mpp, 0, (size_t)(OFF_CNT + 20016 - OFF_MPP) * sizeof(float), stream);

    setup_k<<<1, 256, 0, stream>>>(W1, g1, b1, m1, v1,
                                   W2a, g2a, b2a, m2a, v2a,
                                   W2b, g2b, b2b, m2b, v2b,
                                   (unsigned short*)d_ws, wsf);

    hist_k<<<(N + 255) / 256, 256, 0, stream>>>(unq, cnt, N);
    scan_k<<<1, 1024, 0, stream>>>(cnt, offs, cur, S);

    scatbr2_k<<<(N + 511) / 512, 512, 0, stream>>>(inputs, unq, cur, inpS,
                                                   (const uint4*)d_ws, wsf, mpp, N);

    seg1_k<<<(S + 7) / 8, 512, 0, stream>>>(inpS, offs, (const uint4*)d_ws,
                                            mpp, out, S, N);
}

// Round 6
// 205.673 us; speedup vs baseline: 14.4129x; 1.0598x over previous
//
#include <hip/hip_runtime.h>

#define EPS 1e-3f

// ---------------- workspace layout (float slots) ----------------
// bytes 0..28671 : bf16 fused weights (init_k block 0, each launch)
//   w1ft u16[64][32] @0, w2aft u16[128][32] @4096B, w2bft u16[64][128] @12288B
#define OFF_T2B    7168              // f32[64]
#define OFF_MPP    7232              // f32[64][64] max-pool partials (memset)
#define OFF_CNT    11328             // i32[20016]  histogram (memset w/ mpp)
#define OFF_OFFS   31344             // i32[S+1] CSR offsets
#define OFF_CUR    51360             // i32[S]   scatter cursors
#define OFF_INPS   71424             // bf16[N][16] sorted inputs (32B/pt)

typedef short short8 __attribute__((ext_vector_type(8)));
typedef float f32x4 __attribute__((ext_vector_type(4)));

union U4 { unsigned u[4]; short8 s8; };

__device__ inline unsigned short f2bf(float f) {           // RNE f32->bf16
    unsigned u = __float_as_uint(f);
    return (unsigned short)((u + 0x7FFFu + ((u >> 16) & 1u)) >> 16);
}

// block 0: fuse BN into bf16 weights; blocks 1..: histogram of unq
__global__ __launch_bounds__(256) void init_k(
    const float* __restrict__ W1,
    const float* __restrict__ g1, const float* __restrict__ b1,
    const float* __restrict__ m1, const float* __restrict__ v1,
    const float* __restrict__ W2a,
    const float* __restrict__ g2a, const float* __restrict__ b2a,
    const float* __restrict__ m2a, const float* __restrict__ v2a,
    const float* __restrict__ W2b,
    const float* __restrict__ g2b, const float* __restrict__ b2b,
    const float* __restrict__ m2b, const float* __restrict__ v2b,
    unsigned short* __restrict__ wsu, float* __restrict__ wsf,
    const int* __restrict__ unq, int* __restrict__ cnt, int N)
{
    const int t = threadIdx.x;
    if (blockIdx.x == 0) {
        for (int i = t; i < 64 * 32; i += 256) {        // w1ft [64ch][32k]
            int ch = i >> 5, k = i & 31;
            float s = g1[ch] * rsqrtf(v1[ch] + EPS);
            float val = (k < 16) ? W1[k * 64 + ch] * s
                      : (k == 16 ? b1[ch] - m1[ch] * s : 0.f);
            wsu[i] = f2bf(val);
        }
        for (int i = t; i < 128 * 32; i += 256) {       // w2aft [128ch][32k]
            int ch = i >> 5, k = i & 31;
            float s = g2a[ch] * rsqrtf(v2a[ch] + EPS);
            float val = (k < 16) ? W2a[k * 128 + ch] * s
                      : (k == 16 ? b2a[ch] - m2a[ch] * s : 0.f);
            wsu[2048 + i] = f2bf(val);
        }
        for (int i = t; i < 64 * 128; i += 256) {       // w2bft [64ch][128k]
            int ch = i >> 7, k = i & 127;
            float s = g2b[ch] * rsqrtf(v2b[ch] + EPS);
            wsu[2048 + 4096 + i] = f2bf(W2b[k * 64 + ch] * s);
        }
        if (t < 64) {
            float s = g2b[t] * rsqrtf(v2b[t] + EPS);
            wsf[OFF_T2B + t] = b2b[t] - m2b[t] * s;
        }
    } else {
        const int i = (blockIdx.x - 1) * 256 + t;
        if (i < N) atomicAdd(&cnt[unq[i]], 1);
    }
}

// serial-per-thread two-pass scan: thread t owns elements [t*E, t*E+E)
__global__ __launch_bounds__(1024) void scan_k(
    const int* __restrict__ cnt, int* __restrict__ offs,
    int* __restrict__ cur, int S)
{
    __shared__ int tot[1024];
    const int t = threadIdx.x;
    const int E = (S + 1023) >> 10;
    const int i0 = t * E;
    int run = 0;
    for (int j = 0; j < E; ++j) {
        const int i = i0 + j;
        run += (i < S) ? cnt[i] : 0;
    }
    tot[t] = run;
    __syncthreads();
    for (int d = 1; d < 1024; d <<= 1) {
        int x = (t >= d) ? tot[t - d] : 0;
        __syncthreads();
        tot[t] += x;
        __syncthreads();
    }
    int base = (t == 0) ? 0 : tot[t - 1];
    for (int j = 0; j < E; ++j) {
        const int i = i0 + j;
        if (i < S) {
            offs[i] = base;
            cur[i]  = base;
            base += cnt[i];
        }
    }
    if (t == 1023) offs[S] = tot[1023];
}

// Fused scatter + branch2 + global max-pool. Lanes 0-31 load the input tile
// DIRECTLY in MFMA-B layout (lane(c,g) = point c, k-half g): zero shuffles.
// Scatter: lane g=0 holds inpS[pos*2], g=1 holds inpS[pos*2+1].
__global__ __launch_bounds__(512, 2) void scatbr2_k(
    const float* __restrict__ inputs,
    const int*   __restrict__ unq,
    int*         __restrict__ cur,
    uint4*       __restrict__ inpS,
    const uint4* __restrict__ wsw,
    const float* __restrict__ wsf,
    float* __restrict__ mpp,
    int N)
{
    __shared__ __align__(16) char w2as[8192];    // [128][32] bf16, XOR-swizzled
    __shared__ __align__(16) char w2bs[16384];   // [64][128] bf16
    __shared__ float t2bs[64];
    __shared__ float mpb[64];
    __shared__ __align__(16) char scrs[8][4096]; // per-wave h staging (bf16)

    const int tid = threadIdx.x;
    {
        int u = tid;                              // w2aft: 512 units, rowbytes 64
        *reinterpret_cast<uint4*>(&w2as[(u * 16) ^ (((u >> 2) & 7) << 4)]) = wsw[256 + u];
        for (int v = tid; v < 1024; v += 512)     // w2bft: 1024 units, rowbytes 256
            *reinterpret_cast<uint4*>(&w2bs[(v * 16) ^ (((v >> 4) & 7) << 4)]) = wsw[768 + v];
        if (tid < 64) { t2bs[tid] = wsf[OFF_T2B + tid]; mpb[tid] = 0.f; }
    }
    __syncthreads();

    const int wv   = tid >> 6;
    const int lane = tid & 63;
    const int c = lane & 15;
    const int g = lane >> 4;
    const unsigned swz = (unsigned)(lane & 7) << 4;   // == (c&7)<<4 for all g
    char* scr = scrs[wv];

    const long wave_pt0 = (long)blockIdx.x * 512 + (long)wv * 64;
    const long nrem_w = (long)N - wave_pt0;

    f32x4 t2br[4];
    #pragma unroll
    for (int mt = 0; mt < 4; ++mt)
        t2br[mt] = *reinterpret_cast<const f32x4*>(&t2bs[mt * 16 + g * 4]);

    const f32x4 zero4 = {0.f, 0.f, 0.f, 0.f};
    float mp[16];
    #pragma unroll
    for (int j = 0; j < 16; ++j) mp[j] = 0.f;

    #pragma unroll
    for (int ti = 0; ti < 4; ++ti) {
        if ((long)ti * 16 >= nrem_w) break;              // wave-uniform
        const bool act = (long)(ti * 16 + c) < nrem_w;
        const long pt  = wave_pt0 + ti * 16 + c;

        // ---- B-frag loaded directly from global (lanes g<2), bias g=2 ----
        U4 bf;
        if (g < 2) {
            const long row = act ? pt : (long)(N - 1);
            const float4* p = reinterpret_cast<const float4*>(inputs + row * 16 + g * 8);
            float4 f0 = p[0], f1 = p[1];
            asm("v_cvt_pk_bf16_f32 %0, %1, %2" : "=v"(bf.u[0]) : "v"(f0.x), "v"(f0.y));
            asm("v_cvt_pk_bf16_f32 %0, %1, %2" : "=v"(bf.u[1]) : "v"(f0.z), "v"(f0.w));
            asm("v_cvt_pk_bf16_f32 %0, %1, %2" : "=v"(bf.u[2]) : "v"(f1.x), "v"(f1.y));
            asm("v_cvt_pk_bf16_f32 %0, %1, %2" : "=v"(bf.u[3]) : "v"(f1.z), "v"(f1.w));
            if (!act) { bf.u[0] = 0u; bf.u[1] = 0u; bf.u[2] = 0u; bf.u[3] = 0u; }
        } else {
            bf.u[0] = (g == 2 && act) ? 0x00003F80u : 0u;   // k16 = 1.0 (bias)
            bf.u[1] = 0u; bf.u[2] = 0u; bf.u[3] = 0u;
        }

        // ---- scatter this tile's 16 points into segment-sorted array ----
        int pos = 0;
        if (g == 0 && act) pos = atomicAdd(&cur[unq[pt]], 1);
        pos = __shfl(pos, c, 64);
        if (g < 2 && act)
            inpS[(size_t)pos * 2 + g] = make_uint4(bf.u[0], bf.u[1], bf.u[2], bf.u[3]);

        // ===== h^T = W2aF^T * in^T, relu, bf16 -> scr =====
        #pragma unroll
        for (int mt = 0; mt < 8; ++mt) {
            short8 a = *reinterpret_cast<const short8*>(
                &w2as[(unsigned)((mt * 16 + c) * 64 + g * 16) ^ swz]);
            f32x4 hT = __builtin_amdgcn_mfma_f32_16x16x32_bf16(a, bf.s8, zero4, 0, 0, 0);
            float h0 = fmaxf(hT[0], 0.f), h1 = fmaxf(hT[1], 0.f);
            float h2 = fmaxf(hT[2], 0.f), h3 = fmaxf(hT[3], 0.f);
            unsigned lo, hi;
            asm("v_cvt_pk_bf16_f32 %0, %1, %2" : "=v"(lo) : "v"(h0), "v"(h1));
            asm("v_cvt_pk_bf16_f32 %0, %1, %2" : "=v"(hi) : "v"(h2), "v"(h3));
            *reinterpret_cast<uint2*>(
                &scr[(unsigned)(c * 256 + mt * 32 + g * 8) ^ swz]) = make_uint2(lo, hi);
        }

        // ===== y2^T = W2bF^T * h ; masked running max-pool =====
        f32x4 y2t[4];
        #pragma unroll
        for (int mt = 0; mt < 4; ++mt) y2t[mt] = zero4;
        #pragma unroll
        for (int ks = 0; ks < 4; ++ks) {
            short8 hb = *reinterpret_cast<const short8*>(
                &scr[(unsigned)(c * 256 + ks * 64 + g * 16) ^ swz]);
            #pragma unroll
            for (int mt = 0; mt < 4; ++mt) {
                short8 a = *reinterpret_cast<const short8*>(
                    &w2bs[(unsigned)((mt * 16 + c) * 256 + ks * 64 + g * 16) ^ swz]);
                y2t[mt] = __builtin_amdgcn_mfma_f32_16x16x32_bf16(a, hb, y2t[mt], 0, 0, 0);
            }
        }
        #pragma unroll
        for (int mt = 0; mt < 4; ++mt) {
            #pragma unroll
            for (int r = 0; r < 4; ++r) {
                float v = fmaxf(y2t[mt][r] + t2br[mt][r], 0.f);
                if (act) mp[mt * 4 + r] = fmaxf(mp[mt * 4 + r], v);
            }
        }
    }

    // ---- block max-pool reduce: 16-lane shfl, LDS atomic, one global line ----
    #pragma unroll
    for (int j = 0; j < 16; ++j) {
        float x = mp[j];
        x = fmaxf(x, __shfl_xor(x, 1, 64));
        x = fmaxf(x, __shfl_xor(x, 2, 64));
        x = fmaxf(x, __shfl_xor(x, 4, 64));
        x = fmaxf(x, __shfl_xor(x, 8, 64));
        mp[j] = x;
    }
    if (c == 0) {
        #pragma unroll
        for (int mt = 0; mt < 4; ++mt)
            #pragma unroll
            for (int r = 0; r < 4; ++r)
                atomicMax(reinterpret_cast<int*>(&mpb[mt * 16 + g * 4 + r]),
                          __float_as_int(mp[mt * 4 + r]));
    }
    __syncthreads();
    if (tid < 64)
        atomicMax(reinterpret_cast<int*>(mpp + (blockIdx.x & 63) * 64 + tid),
                  __float_as_int(mpb[tid]));
}

// One wave per segment on SORTED bf16 inputs: B-frag = direct 16B load,
// 4 MFMA/tile, in-register sum/max, write final shuffled 768B row to out.
__global__ __launch_bounds__(512) void seg1_k(
    const uint4* __restrict__ inpS,
    const int*   __restrict__ offs,
    const uint4* __restrict__ wsw,
    const float* __restrict__ mpp,
    float* __restrict__ out,
    int S, int Npt)
{
    __shared__ __align__(16) char w1s[4096];     // [64][32] bf16, XOR-swizzled
    __shared__ float mps[64];
    __shared__ float scr3[8][192];

    const int tid = threadIdx.x;
    if (tid < 256) {
        int u = tid;
        *reinterpret_cast<uint4*>(&w1s[(u * 16) ^ (((u >> 2) & 7) << 4)]) = wsw[u];
    }
    if (tid < 64) {
        float m = 0.f;
        #pragma unroll
        for (int s = 0; s < 64; ++s)
            m = fmaxf(m, mpp[s * 64 + tid]);
        mps[tid] = m;
    }
    __syncthreads();

    const int wv   = tid >> 6;
    const int lane = tid & 63;
    const int seg  = blockIdx.x * 8 + wv;
    if (seg >= S) return;

    const int c = lane & 15;
    const int g = lane >> 4;
    const unsigned swz = (unsigned)(lane & 7) << 4;

    const int start = offs[seg];
    const int end   = offs[seg + 1];

    const f32x4 zero4 = {0.f, 0.f, 0.f, 0.f};
    f32x4 as[4], am[4];
    #pragma unroll
    for (int mt = 0; mt < 4; ++mt) { as[mt] = zero4; am[mt] = zero4; }

    for (int base = start; base < end; base += 64) {
        const int nrem = end - base;
        #pragma unroll
        for (int ti = 0; ti < 4; ++ti) {
            if (ti * 16 >= nrem) break;                 // wave-uniform
            const bool act = (ti * 16 + c) < nrem;

            U4 bf;
            if (g < 2) {
                int row = min(base + ti * 16 + c, Npt - 1);
                uint4 q = inpS[(size_t)row * 2 + g];
                bf.u[0] = act ? q.x : 0u;
                bf.u[1] = act ? q.y : 0u;
                bf.u[2] = act ? q.z : 0u;
                bf.u[3] = act ? q.w : 0u;
            } else {
                bf.u[0] = (g == 2 && act) ? 0x00003F80u : 0u;
                bf.u[1] = 0u; bf.u[2] = 0u; bf.u[3] = 0u;
            }
            #pragma unroll
            for (int mt = 0; mt < 4; ++mt) {
                short8 a = *reinterpret_cast<const short8*>(
                    &w1s[(unsigned)((mt * 16 + c) * 64 + g * 16) ^ swz]);
                f32x4 y1t = __builtin_amdgcn_mfma_f32_16x16x32_bf16(a, bf.s8, zero4, 0, 0, 0);
                #pragma unroll
                for (int r = 0; r < 4; ++r) {
                    float v = fmaxf(y1t[r], 0.f);       // inactive cols give 0
                    as[mt][r] += v;
                    am[mt][r]  = fmaxf(am[mt][r], v);
                }
            }
        }
    }

    // ---- reduce across the 16 column-lanes ----
    #pragma unroll
    for (int mt = 0; mt < 4; ++mt) {
        #pragma unroll
        for (int r = 0; r < 4; ++r) {
            float xs = as[mt][r], xm = am[mt][r];
            xs += __shfl_xor(xs, 1, 64);  xm = fmaxf(xm, __shfl_xor(xm, 1, 64));
            xs += __shfl_xor(xs, 2, 64);  xm = fmaxf(xm, __shfl_xor(xm, 2, 64));
            xs += __shfl_xor(xs, 4, 64);  xm = fmaxf(xm, __shfl_xor(xm, 4, 64));
            xs += __shfl_xor(xs, 8, 64);  xm = fmaxf(xm, __shfl_xor(xm, 8, 64));
            as[mt][r] = xs; am[mt][r] = xm;
        }
    }

    // ---- stage channel-shuffled 192 floats, then 3 coalesced line writes ----
    float* sr = scr3[wv];
    if (c == 0) {
        #pragma unroll
        for (int mt = 0; mt < 4; ++mt)
            #pragma unroll
            for (int r = 0; r < 4; ++r) {
                const int ch = mt * 16 + g * 4 + r;
                sr[ch * 3 + 0] = as[mt][r];
                sr[ch * 3 + 1] = am[mt][r];
            }
    }
    sr[lane * 3 + 2] = mps[lane];
    __builtin_amdgcn_wave_barrier();
    asm volatile("s_waitcnt lgkmcnt(0)" ::: "memory");
    __builtin_amdgcn_sched_barrier(0);

    float* o = out + (size_t)seg * 192;
    #pragma unroll
    for (int p = 0; p < 3; ++p)
        o[p * 64 + lane] = sr[p * 64 + lane];
}

extern "C" void kernel_launch(void* const* d_in, const int* in_sizes, int n_in,
                              void* d_out, int out_size, void* d_ws, size_t ws_size,
                              hipStream_t stream)
{
    const float* inputs = (const float*)d_in[0];
    const int*   unq    = (const int*)d_in[1];
    const float* W1  = (const float*)d_in[3];
    const float* g1  = (const float*)d_in[4];
    const float* b1  = (const float*)d_in[5];
    const float* m1  = (const float*)d_in[6];
    const float* v1  = (const float*)d_in[7];
    const float* W2a = (const float*)d_in[8];
    const float* g2a = (const float*)d_in[9];
    const float* b2a = (const float*)d_in[10];
    const float* m2a = (const float*)d_in[11];
    const float* v2a = (const float*)d_in[12];
    const float* W2b = (const float*)d_in[13];
    const float* g2b = (const float*)d_in[14];
    const float* b2b = (const float*)d_in[15];
    const float* m2b = (const float*)d_in[16];
    const float* v2b = (const float*)d_in[17];

    float* wsf = (float*)d_ws;
    float* out = (float*)d_out;
    const int N = in_sizes[0] / 16;
    const int S = out_size / 192;

    float* mpp  = wsf + OFF_MPP;
    int*   cnt  = (int*)(wsf + OFF_CNT);
    int*   offs = (int*)(wsf + OFF_OFFS);
    int*   cur  = (int*)(wsf + OFF_CUR);
    uint4* inpS = (uint4*)(wsf + OFF_INPS);

    // zero mpp + cnt (contiguous region)
    hipMemsetAsync(mpp, 0, (size_t)(OFF_CNT + 20016 - OFF_MPP) * sizeof(float), stream);

    init_k<<<1 + (N + 255) / 256, 256, 0, stream>>>(
        W1, g1, b1, m1, v1, W2a, g2a, b2a, m2a, v2a, W2b, g2b, b2b, m2b, v2b,
        (unsigned short*)d_ws, wsf, unq, cnt, N);

    scan_k<<<1, 1024, 0, stream>>>(cnt, offs, cur, S);

    scatbr2_k<<<(N + 511) / 512, 512, 0, stream>>>(inputs, unq, cur, inpS,
                                                   (const uint4*)d_ws, wsf, mpp, N);

    seg1_k<<<(S + 7) / 8, 512, 0, stream>>>(inpS, offs, (const uint4*)d_ws,
                                            mpp, out, S, N);
}